// Round 1
// baseline (1084.453 us; speedup 1.0000x reference)
//
#include <hip/hip_runtime.h>
#include <cstdint>
#include <cstddef>

typedef __bf16 bf16;
typedef __bf16 bf16x8 __attribute__((ext_vector_type(8)));
typedef float  f32x4  __attribute__((ext_vector_type(4)));

#define MFMA16(a, b, c) __builtin_amdgcn_mfma_f32_16x16x32_bf16((a), (b), (c), 0, 0, 0)

// ---------------------------------------------------------------------------
// Helpers
// ---------------------------------------------------------------------------
static __device__ __forceinline__ unsigned pack_bf16x2(float a, float b) {
    union { unsigned u; bf16 h[2]; } t;
    t.h[0] = (bf16)a; t.h[1] = (bf16)b;
    return t.u;
}

// ---------------------------------------------------------------------------
// LayerNorm: one wave per 512-element row, fp32 in, bf16 out
// ---------------------------------------------------------------------------
__global__ __launch_bounds__(256) void ln_kernel(const float* __restrict__ x,
                                                 const float* __restrict__ g,
                                                 const float* __restrict__ b,
                                                 bf16* __restrict__ out) {
    int row  = blockIdx.x * 4 + (threadIdx.x >> 6);
    int lane = threadIdx.x & 63;
    const float* xr = x + (size_t)row * 512 + lane * 8;
    float4 v0 = *(const float4*)xr;
    float4 v1 = *(const float4*)(xr + 4);
    float s  = v0.x + v0.y + v0.z + v0.w + v1.x + v1.y + v1.z + v1.w;
    float ss = v0.x*v0.x + v0.y*v0.y + v0.z*v0.z + v0.w*v0.w
             + v1.x*v1.x + v1.y*v1.y + v1.z*v1.z + v1.w*v1.w;
#pragma unroll
    for (int off = 1; off < 64; off <<= 1) {
        s  += __shfl_xor(s, off, 64);
        ss += __shfl_xor(ss, off, 64);
    }
    float mean = s * (1.0f / 512.0f);
    float var  = ss * (1.0f / 512.0f) - mean * mean;
    float rstd = rsqrtf(var + 1e-5f);
    const float* gr = g + lane * 8;
    const float* br = b + lane * 8;
    float4 g0 = *(const float4*)gr, g1 = *(const float4*)(gr + 4);
    float4 b0 = *(const float4*)br, b1 = *(const float4*)(br + 4);
    bf16x8 o;
    o[0] = (bf16)((v0.x - mean) * rstd * g0.x + b0.x);
    o[1] = (bf16)((v0.y - mean) * rstd * g0.y + b0.y);
    o[2] = (bf16)((v0.z - mean) * rstd * g0.z + b0.z);
    o[3] = (bf16)((v0.w - mean) * rstd * g0.w + b0.w);
    o[4] = (bf16)((v1.x - mean) * rstd * g1.x + b1.x);
    o[5] = (bf16)((v1.y - mean) * rstd * g1.y + b1.y);
    o[6] = (bf16)((v1.z - mean) * rstd * g1.z + b1.z);
    o[7] = (bf16)((v1.w - mean) * rstd * g1.w + b1.w);
    *(uint4*)(out + (size_t)row * 512 + lane * 8) = *(uint4*)&o;
}

// ---------------------------------------------------------------------------
// Generic 128x128-tile bf16 GEMM, A bf16 [M,lda], B fp32 [K,ldb] (converted).
// EPI 0: scatter to q/k/v [3][BH][8192][64] bf16
// EPI 1: out fp32 = acc + res          (attn out-proj + residual)
// EPI 2: out fp32 = acc + res + bias[n] (ff2 + b2 + residual)
// ---------------------------------------------------------------------------
template <int EPI>
__global__ __launch_bounds__(256) void gemm128_kernel(
    const bf16* __restrict__ A, int lda,
    const float* __restrict__ B, int ldb,
    int Kloop, int Ksrc,
    bf16* __restrict__ Cb, float* __restrict__ Cf,
    const float* __restrict__ res, const float* __restrict__ bias) {
    __shared__ __align__(16) bf16 As[128][72];
    __shared__ __align__(16) bf16 Bs[128][72];
    const int tid  = threadIdx.x;
    const int wid  = tid >> 6;
    const int lane = tid & 63;
    const int quad = lane >> 4;
    const int l16  = lane & 15;
    const int wm   = wid >> 1;
    const int wn   = wid & 1;
    const int m0   = blockIdx.y * 128;
    const int n0   = blockIdx.x * 128;

    f32x4 z4 = {0.f, 0.f, 0.f, 0.f};
    f32x4 acc[4][4];
#pragma unroll
    for (int i = 0; i < 4; ++i)
#pragma unroll
        for (int j = 0; j < 4; ++j) acc[i][j] = z4;

    for (int kt = 0; kt < Kloop; kt += 64) {
        __syncthreads();
        // Stage A (bf16, 16B vector loads, contiguous LDS writes)
#pragma unroll
        for (int p = 0; p < 4; ++p) {
            int c  = tid + (p << 8);
            int r  = c >> 3;
            int k8 = (c & 7) << 3;
            *(uint4*)&As[r][k8] =
                *(const uint4*)(A + (size_t)(m0 + r) * lda + kt + k8);
        }
        // Stage B transposed [n][k]: fp32 loads, bf16x2-packed b32 LDS writes
#pragma unroll
        for (int p = 0; p < 4; ++p) {
            int nn = (tid & 31) + (p << 5);
#pragma unroll
            for (int qq = 0; qq < 4; ++qq) {
                int rk  = ((tid >> 5) << 1) + (qq << 4);
                int gk0 = kt + rk;
                float v0 = 0.f, v1 = 0.f;
                if (Ksrc >= Kloop || gk0 < Ksrc)
                    v0 = B[(size_t)gk0 * ldb + n0 + nn];
                if (Ksrc >= Kloop || gk0 + 1 < Ksrc)
                    v1 = B[(size_t)(gk0 + 1) * ldb + n0 + nn];
                *(unsigned*)&Bs[nn][rk] = pack_bf16x2(v0, v1);
            }
        }
        __syncthreads();
#pragma unroll
        for (int ks = 0; ks < 2; ++ks) {
            bf16x8 af[4], bfr[4];
#pragma unroll
            for (int i = 0; i < 4; ++i)
                af[i] = *(const bf16x8*)&As[wm * 64 + i * 16 + l16][ks * 32 + quad * 8];
#pragma unroll
            for (int j = 0; j < 4; ++j)
                bfr[j] = *(const bf16x8*)&Bs[wn * 64 + j * 16 + l16][ks * 32 + quad * 8];
#pragma unroll
            for (int i = 0; i < 4; ++i)
#pragma unroll
                for (int j = 0; j < 4; ++j)
                    acc[i][j] = MFMA16(af[i], bfr[j], acc[i][j]);
        }
    }

#pragma unroll
    for (int i = 0; i < 4; ++i)
#pragma unroll
        for (int j = 0; j < 4; ++j)
#pragma unroll
            for (int r = 0; r < 4; ++r) {
                int m = m0 + wm * 64 + i * 16 + quad * 4 + r;
                int n = n0 + wn * 64 + j * 16 + l16;
                float v = acc[i][j][r];
                if (EPI == 0) {
                    int which = n >> 9, hh = (n >> 6) & 7, d = n & 63;
                    int bb = m >> 13, nn = m & 8191;
                    Cb[(size_t)which * 8388608 +
                       ((size_t)(bb * 8 + hh) * 8192 + nn) * 64 + d] = (bf16)v;
                } else if (EPI == 1) {
                    size_t idx = (size_t)m * 512 + n;
                    Cf[idx] = v + res[idx];
                } else {
                    size_t idx = (size_t)m * 512 + n;
                    Cf[idx] = v + res[idx] + bias[n];
                }
            }
}

// ---------------------------------------------------------------------------
// l2norm + qk scale + xPos rotary, in place on q/k [BH,8192,64].
// One block per (b,n); wave = head (8 waves), lane = dim.
// ---------------------------------------------------------------------------
__global__ __launch_bounds__(512) void rot_kernel(bf16* __restrict__ qb,
                                                  bf16* __restrict__ kb,
                                                  const float* __restrict__ qscale,
                                                  const float* __restrict__ kscale) {
    int pos = blockIdx.x;
    int b = pos >> 13, n = pos & 8191;
    int h = threadIdx.x >> 6;
    int d = threadIdx.x & 63;
    size_t idx = ((size_t)(b * 8 + h) * 8192 + n) * 64 + d;
    float qv = (float)qb[idx];
    float kv = (float)kb[idx];
    float sq = qv * qv, sk = kv * kv;
#pragma unroll
    for (int off = 1; off < 64; off <<= 1) {
        sq += __shfl_xor(sq, off, 64);
        sk += __shfl_xor(sk, off, 64);
    }
    qv = qv / fmaxf(sqrtf(sq), 1e-12f) * qscale[d];
    kv = kv / fmaxf(sqrtf(sk), 1e-12f) * kscale[d];
    int i2 = d & 31;
    float invf = powf(10000.0f, -(float)i2 / 32.0f);
    float th = (float)n * invf;
    float c = cosf(th), s = sinf(th);
    float sv = ((float)(2 * i2) + 25.6f) / 89.6f;
    float pw = ((float)n - 4096.0f) * (1.0f / 256.0f);
    float xs = powf(sv, pw);
    float qo = __shfl_xor(qv, 32, 64);
    float ko = __shfl_xor(kv, 32, 64);
    float rhq = (d < 32) ? -qo : qo;
    float rhk = (d < 32) ? -ko : ko;
    qb[idx] = (bf16)((qv * c + rhq * s) * xs);
    kb[idx] = (bf16)((kv * c + rhk * s) / xs);
}

// ---------------------------------------------------------------------------
// Local windowed attention (flash-style), window 512, lookback one window.
// Block = (bh, 64 query rows); wave = 16 rows. K/V chunks of 128 in LDS.
// Output written as [B, N, H*64] bf16 for the out-proj GEMM.
// ---------------------------------------------------------------------------
__global__ __launch_bounds__(256) void attn_kernel(const bf16* __restrict__ q,
                                                   const bf16* __restrict__ k,
                                                   const bf16* __restrict__ v,
                                                   bf16* __restrict__ o) {
    __shared__ __align__(16) bf16 Ks[128][72];
    __shared__ __align__(16) bf16 Vt[64][136];
    __shared__ __align__(16) bf16 Ps[4][16][136];
    const int tid  = threadIdx.x;
    const int wid  = tid >> 6;
    const int lane = tid & 63;
    const int quad = lane >> 4;
    const int l16  = lane & 15;
    const int bh   = blockIdx.y;
    const int q0   = blockIdx.x * 64;
    const size_t qbase = (size_t)bh * 8192;

    bf16x8 aq[2];
    {
        int qrow = q0 + wid * 16 + l16;
        const bf16* qp = q + (qbase + qrow) * 64 + quad * 8;
        aq[0] = *(const bf16x8*)qp;
        aq[1] = *(const bf16x8*)(qp + 32);
    }
    f32x4 z4 = {0.f, 0.f, 0.f, 0.f};
    f32x4 accO[4];
    float mrow[4], lrow[4];
#pragma unroll
    for (int r = 0; r < 4; ++r) {
        accO[r] = z4;
        mrow[r] = -__builtin_inff();
        lrow[r] = 0.f;
    }

    int klo = q0 - 512;
    if (klo < 0) klo = 0;
    for (int kc = klo; kc < q0 + 64; kc += 128) {
        __syncthreads();
        // Stage K [key][d] and V transposed [d][key]
#pragma unroll
        for (int p = 0; p < 4; ++p) {
            int c  = tid + (p << 8);
            int key = c >> 3;
            int d0 = (c & 7) << 3;
            int gk = kc + key;
            uint4 kvu = make_uint4(0, 0, 0, 0);
            uint4 vvu = make_uint4(0, 0, 0, 0);
            if (gk < 8192) {
                kvu = *(const uint4*)(k + (qbase + gk) * 64 + d0);
                vvu = *(const uint4*)(v + (qbase + gk) * 64 + d0);
            }
            *(uint4*)&Ks[key][d0] = kvu;
            union { uint4 u; bf16 h[8]; } tv;
            tv.u = vvu;
#pragma unroll
            for (int j = 0; j < 8; ++j) Vt[d0 + j][key] = tv.h[j];
        }
        __syncthreads();
        // S = Q K^T for this wave's 16 rows x 128 keys
        f32x4 s[8];
#pragma unroll
        for (int ns = 0; ns < 8; ++ns) {
            s[ns] = z4;
            bf16x8 b0 = *(const bf16x8*)&Ks[ns * 16 + l16][quad * 8];
            s[ns] = MFMA16(aq[0], b0, s[ns]);
            bf16x8 b1 = *(const bf16x8*)&Ks[ns * 16 + l16][32 + quad * 8];
            s[ns] = MFMA16(aq[1], b1, s[ns]);
        }
        // scale + mask + row stats
        float mx[4] = {-__builtin_inff(), -__builtin_inff(),
                       -__builtin_inff(), -__builtin_inff()};
#pragma unroll
        for (int ns = 0; ns < 8; ++ns)
#pragma unroll
            for (int r = 0; r < 4; ++r) {
                int gi = q0 + wid * 16 + quad * 4 + r;
                int gj = kc + ns * 16 + l16;
                float sv = s[ns][r] * 8.0f;
                if (gj > gi || gj < gi - 512) sv = -__builtin_inff();
                s[ns][r] = sv;
                mx[r] = fmaxf(mx[r], sv);
            }
#pragma unroll
        for (int r = 0; r < 4; ++r) {
#pragma unroll
            for (int off = 1; off < 16; off <<= 1)
                mx[r] = fmaxf(mx[r], __shfl_xor(mx[r], off, 64));
        }
        float alpha[4], rs[4];
#pragma unroll
        for (int r = 0; r < 4; ++r) {
            float mn = fmaxf(mrow[r], mx[r]);
            alpha[r] = (mn == -__builtin_inff()) ? 1.0f : __expf(mrow[r] - mn);
            mrow[r] = mn;
            rs[r] = 0.f;
        }
#pragma unroll
        for (int ns = 0; ns < 8; ++ns)
#pragma unroll
            for (int r = 0; r < 4; ++r) {
                float pv = (s[ns][r] == -__builtin_inff())
                               ? 0.f
                               : __expf(s[ns][r] - mrow[r]);
                rs[r] += pv;
                Ps[wid][quad * 4 + r][ns * 16 + l16] = (bf16)pv;
            }
#pragma unroll
        for (int r = 0; r < 4; ++r) {
            float t = rs[r];
#pragma unroll
            for (int off = 1; off < 16; off <<= 1) t += __shfl_xor(t, off, 64);
            lrow[r] = lrow[r] * alpha[r] + t;
        }
#pragma unroll
        for (int ds = 0; ds < 4; ++ds)
#pragma unroll
            for (int r = 0; r < 4; ++r) accO[ds][r] *= alpha[r];
        __builtin_amdgcn_sched_barrier(0);  // keep P writes before P reads
        // O += P V
#pragma unroll
        for (int ks2 = 0; ks2 < 4; ++ks2) {
            bf16x8 ap = *(const bf16x8*)&Ps[wid][l16][ks2 * 32 + quad * 8];
#pragma unroll
            for (int ds = 0; ds < 4; ++ds) {
                bf16x8 bv = *(const bf16x8*)&Vt[ds * 16 + l16][ks2 * 32 + quad * 8];
                accO[ds] = MFMA16(ap, bv, accO[ds]);
            }
        }
    }
    int bb = bh >> 3, hh = bh & 7;
#pragma unroll
    for (int ds = 0; ds < 4; ++ds)
#pragma unroll
        for (int r = 0; r < 4; ++r) {
            int m = q0 + wid * 16 + quad * 4 + r;
            float ov = accO[ds][r] / lrow[r];
            o[((size_t)(bb * 8192 + m)) * 512 + hh * 64 + ds * 16 + l16] = (bf16)ov;
        }
}

// ---------------------------------------------------------------------------
// FF1: computes both halves of h2 @ ff_W1 + b1 and writes a*gelu(gate)
// directly as bf16 [16384][1408] (cols >= 1365 zero-padded).
// Block tile 128(m) x 64(n per half); wave tile 64x32 per half.
// ---------------------------------------------------------------------------
__global__ __launch_bounds__(256) void ff1_kernel(const bf16* __restrict__ A,
                                                  const float* __restrict__ W1,
                                                  const float* __restrict__ b1,
                                                  bf16* __restrict__ act) {
    __shared__ __align__(16) bf16 As[128][72];
    __shared__ __align__(16) bf16 Bsa[64][72];
    __shared__ __align__(16) bf16 Bsg[64][72];
    const int tid  = threadIdx.x;
    const int wid  = tid >> 6;
    const int lane = tid & 63;
    const int quad = lane >> 4;
    const int l16  = lane & 15;
    const int wm   = wid >> 1;
    const int wn   = wid & 1;
    const int m0   = blockIdx.y * 128;
    const int n0   = blockIdx.x * 64;

    f32x4 z4 = {0.f, 0.f, 0.f, 0.f};
    f32x4 aa[4][2], ag[4][2];
#pragma unroll
    for (int i = 0; i < 4; ++i)
#pragma unroll
        for (int j = 0; j < 2; ++j) { aa[i][j] = z4; ag[i][j] = z4; }

    for (int kt = 0; kt < 512; kt += 64) {
        __syncthreads();
#pragma unroll
        for (int p = 0; p < 4; ++p) {
            int c  = tid + (p << 8);
            int r  = c >> 3;
            int k8 = (c & 7) << 3;
            *(uint4*)&As[r][k8] =
                *(const uint4*)(A + (size_t)(m0 + r) * 512 + kt + k8);
        }
#pragma unroll
        for (int p = 0; p < 2; ++p) {
            int nn = (tid & 31) + (p << 5);
            int gn = n0 + nn;
            bool ok = gn < 1365;
#pragma unroll
            for (int qq = 0; qq < 4; ++qq) {
                int rk  = ((tid >> 5) << 1) + (qq << 4);
                int gk0 = kt + rk;
                float a0 = 0.f, a1 = 0.f, g0 = 0.f, g1 = 0.f;
                if (ok) {
                    a0 = W1[(size_t)gk0 * 2730 + gn];
                    a1 = W1[(size_t)(gk0 + 1) * 2730 + gn];
                    g0 = W1[(size_t)gk0 * 2730 + 1365 + gn];
                    g1 = W1[(size_t)(gk0 + 1) * 2730 + 1365 + gn];
                }
                *(unsigned*)&Bsa[nn][rk] = pack_bf16x2(a0, a1);
                *(unsigned*)&Bsg[nn][rk] = pack_bf16x2(g0, g1);
            }
        }
        __syncthreads();
#pragma unroll
        for (int ks = 0; ks < 2; ++ks) {
            bf16x8 af[4];
#pragma unroll
            for (int i = 0; i < 4; ++i)
                af[i] = *(const bf16x8*)&As[wm * 64 + i * 16 + l16][ks * 32 + quad * 8];
#pragma unroll
            for (int j = 0; j < 2; ++j) {
                bf16x8 ba = *(const bf16x8*)&Bsa[wn * 32 + j * 16 + l16][ks * 32 + quad * 8];
                bf16x8 bg = *(const bf16x8*)&Bsg[wn * 32 + j * 16 + l16][ks * 32 + quad * 8];
#pragma unroll
                for (int i = 0; i < 4; ++i) {
                    aa[i][j] = MFMA16(af[i], ba, aa[i][j]);
                    ag[i][j] = MFMA16(af[i], bg, ag[i][j]);
                }
            }
        }
    }

#pragma unroll
    for (int i = 0; i < 4; ++i)
#pragma unroll
        for (int j = 0; j < 2; ++j)
#pragma unroll
            for (int r = 0; r < 4; ++r) {
                int m  = m0 + wm * 64 + i * 16 + quad * 4 + r;
                int n  = n0 + wn * 32 + j * 16 + l16;
                bf16 outv = (bf16)0.f;
                if (n < 1365) {
                    float av = aa[i][j][r] + b1[n];
                    float gv = ag[i][j][r] + b1[1365 + n];
                    float gel = 0.5f * gv * (1.0f + erff(gv * 0.70710678118f));
                    outv = (bf16)(av * gel);
                }
                act[(size_t)m * 1408 + n] = outv;
            }
}

// ---------------------------------------------------------------------------
// Launch
// ---------------------------------------------------------------------------
extern "C" void kernel_launch(void* const* d_in, const int* in_sizes, int n_in,
                              void* d_out, int out_size, void* d_ws, size_t ws_size,
                              hipStream_t stream) {
    const float* x      = (const float*)d_in[0];
    const float* ln1g   = (const float*)d_in[1];
    const float* ln1b   = (const float*)d_in[2];
    const float* Wqkv   = (const float*)d_in[3];
    const float* qscale = (const float*)d_in[4];
    const float* kscale = (const float*)d_in[5];
    const float* Wout   = (const float*)d_in[6];
    const float* ln2g   = (const float*)d_in[7];
    const float* ln2b   = (const float*)d_in[8];
    const float* W1     = (const float*)d_in[9];
    const float* b1     = (const float*)d_in[10];
    const float* W2     = (const float*)d_in[11];
    const float* b2     = (const float*)d_in[12];
    float* out = (float*)d_out;

    char* ws = (char*)d_ws;
    const size_t MB = 1024 * 1024;
    bf16*  h   = (bf16*)(ws);             // 16 MB   (reused: attn out o, then h2)
    bf16*  qb  = (bf16*)(ws + 16 * MB);   // 16 MB   (reused later by act)
    bf16*  kb  = (bf16*)(ws + 32 * MB);   // 16 MB
    bf16*  vb  = (bf16*)(ws + 48 * MB);   // 16 MB
    float* x1  = (float*)(ws + 64 * MB);  // 32 MB
    bf16*  ob  = h;                       // slot 0 reuse (h dead after qkv GEMM)
    bf16*  h2  = h;                       // slot 0 reuse (ob dead after out-proj)
    bf16*  act = (bf16*)(ws + 16 * MB);   // 44 MB   (q/k/v dead after attention)

    // 1. LN1
    ln_kernel<<<4096, 256, 0, stream>>>(x, ln1g, ln1b, h);
    // 2. QKV GEMM -> per-head q/k/v
    gemm128_kernel<0><<<dim3(12, 128), 256, 0, stream>>>(
        h, 512, Wqkv, 1536, 512, 512, qb, nullptr, nullptr, nullptr);
    // 3. l2norm + scale + rotary (in place)
    rot_kernel<<<16384, 512, 0, stream>>>(qb, kb, qscale, kscale);
    // 4. local attention
    attn_kernel<<<dim3(128, 16), 256, 0, stream>>>(qb, kb, vb, ob);
    // 5. out-proj + residual -> x1 (fp32)
    gemm128_kernel<1><<<dim3(4, 128), 256, 0, stream>>>(
        ob, 512, Wout, 512, 512, 512, nullptr, x1, x, nullptr);
    // 6. LN2
    ln_kernel<<<4096, 256, 0, stream>>>(x1, ln2g, ln2b, h2);
    // 7. FF1 fused dual-half + gelu -> act (zero-padded to 1408 cols)
    ff1_kernel<<<dim3(22, 128), 256, 0, stream>>>(h2, W1, b1, act);
    // 8. FF2 + b2 + residual -> out
    gemm128_kernel<2><<<dim3(4, 128), 256, 0, stream>>>(
        act, 1408, W2, 512, 1408, 1365, nullptr, out, x1, b2);
}

// Round 2
// 500.478 us; speedup vs baseline: 2.1668x; 2.1668x over previous
//
#include <hip/hip_runtime.h>
#include <cstdint>
#include <cstddef>

typedef __bf16 bf16;
typedef __bf16 bf16x8 __attribute__((ext_vector_type(8)));
typedef float  f32x4  __attribute__((ext_vector_type(4)));

#define MFMA16(a, b, c) __builtin_amdgcn_mfma_f32_16x16x32_bf16((a), (b), (c), 0, 0, 0)

// async global->LDS, 16B per lane; data lands at wave-uniform base + lane*16
static __device__ __forceinline__ void gld16(const bf16* g, bf16* l) {
    __builtin_amdgcn_global_load_lds(
        (const __attribute__((address_space(1))) void*)g,
        (__attribute__((address_space(3))) void*)l, 16, 0, 0);
}

// ---------------------------------------------------------------------------
// Weight prep: fp32 [K][N] -> bf16 [Nrows][Kpad] (transposed, zero-padded)
// ---------------------------------------------------------------------------
__global__ __launch_bounds__(256) void tcvt_kernel(const float* __restrict__ src,
                                                   bf16* __restrict__ dst,
                                                   int K, int N, int Kpad, int Nrows) {
    __shared__ float t[32][33];
    int k0 = blockIdx.x * 32, n0 = blockIdx.y * 32;
#pragma unroll
    for (int i = threadIdx.y; i < 32; i += 8) {
        int k = k0 + i, n = n0 + threadIdx.x;
        t[i][threadIdx.x] = (k < K && n < N) ? src[(size_t)k * N + n] : 0.f;
    }
    __syncthreads();
#pragma unroll
    for (int i = threadIdx.y; i < 32; i += 8) {
        int n = n0 + i, k = k0 + threadIdx.x;
        if (n < Nrows && k < Kpad) dst[(size_t)n * Kpad + k] = (bf16)t[threadIdx.x][i];
    }
}

// ---------------------------------------------------------------------------
// LayerNorm: one wave per 512-element row, fp32 in, bf16 out
// ---------------------------------------------------------------------------
__global__ __launch_bounds__(256) void ln_kernel(const float* __restrict__ x,
                                                 const float* __restrict__ g,
                                                 const float* __restrict__ b,
                                                 bf16* __restrict__ out) {
    int row  = blockIdx.x * 4 + (threadIdx.x >> 6);
    int lane = threadIdx.x & 63;
    const float* xr = x + (size_t)row * 512 + lane * 8;
    float4 v0 = *(const float4*)xr;
    float4 v1 = *(const float4*)(xr + 4);
    float s  = v0.x + v0.y + v0.z + v0.w + v1.x + v1.y + v1.z + v1.w;
    float ss = v0.x*v0.x + v0.y*v0.y + v0.z*v0.z + v0.w*v0.w
             + v1.x*v1.x + v1.y*v1.y + v1.z*v1.z + v1.w*v1.w;
#pragma unroll
    for (int off = 1; off < 64; off <<= 1) {
        s  += __shfl_xor(s, off, 64);
        ss += __shfl_xor(ss, off, 64);
    }
    float mean = s * (1.0f / 512.0f);
    float var  = ss * (1.0f / 512.0f) - mean * mean;
    float rstd = rsqrtf(var + 1e-5f);
    const float* gr = g + lane * 8;
    const float* br = b + lane * 8;
    float4 g0 = *(const float4*)gr, g1 = *(const float4*)(gr + 4);
    float4 b0 = *(const float4*)br, b1 = *(const float4*)(br + 4);
    bf16x8 o;
    o[0] = (bf16)((v0.x - mean) * rstd * g0.x + b0.x);
    o[1] = (bf16)((v0.y - mean) * rstd * g0.y + b0.y);
    o[2] = (bf16)((v0.z - mean) * rstd * g0.z + b0.z);
    o[3] = (bf16)((v0.w - mean) * rstd * g0.w + b0.w);
    o[4] = (bf16)((v1.x - mean) * rstd * g1.x + b1.x);
    o[5] = (bf16)((v1.y - mean) * rstd * g1.y + b1.y);
    o[6] = (bf16)((v1.z - mean) * rstd * g1.z + b1.z);
    o[7] = (bf16)((v1.w - mean) * rstd * g1.w + b1.w);
    *(uint4*)(out + (size_t)row * 512 + lane * 8) = *(uint4*)&o;
}

// ---------------------------------------------------------------------------
// m97-style bf16 GEMM: A [M][K], B [N][K] (pre-transposed bf16 weights).
// 128x128 tile, BK=64, global_load_lds staging, XOR-swizzled LDS chunks.
// EPI 0: scatter to q/k/v [3][BH][8192][64] bf16
// EPI 1: Cf = acc + res            (out-proj + residual, Cf may be d_out)
// EPI 2: Cf = acc + res + bias[n]  (ff2; Cf == res == d_out, within-thread RAW)
// ---------------------------------------------------------------------------
template <int EPI>
__global__ __launch_bounds__(256) void gemm_bt(
    const bf16* __restrict__ A, const bf16* __restrict__ Bm, int K,
    bf16* __restrict__ Cb, float* Cf,
    const float* res, const float* __restrict__ bias) {
    __shared__ __align__(16) bf16 As[128 * 64];
    __shared__ __align__(16) bf16 Bs[128 * 64];
    const int tid  = threadIdx.x;
    const int wid  = tid >> 6;
    const int lane = tid & 63;
    const int quad = lane >> 4;
    const int l16  = lane & 15;
    const int wm   = wid >> 1;
    const int wn   = wid & 1;
    const int m0   = blockIdx.y * 128;
    const int n0   = blockIdx.x * 128;

    f32x4 z4 = {0.f, 0.f, 0.f, 0.f};
    f32x4 acc[4][4];
#pragma unroll
    for (int i = 0; i < 4; ++i)
#pragma unroll
        for (int j = 0; j < 4; ++j) acc[i][j] = z4;

    for (int kt = 0; kt < K; kt += 64) {
        __syncthreads();
#pragma unroll
        for (int p = 0; p < 4; ++p) {
            int c   = tid + (p << 8);       // 0..1023 chunk id
            int row = c >> 3;
            int sl  = c & 7;                // LDS slot within row
            int g   = sl ^ (row & 7);       // global chunk (XOR swizzle)
            gld16(A  + (size_t)(m0 + row) * K + kt + g * 8, As + c * 8);
            gld16(Bm + (size_t)(n0 + row) * K + kt + g * 8, Bs + c * 8);
        }
        __syncthreads();
#pragma unroll
        for (int ks = 0; ks < 2; ++ks) {
            bf16x8 af[4], bfr[4];
#pragma unroll
            for (int i = 0; i < 4; ++i) {
                int r = wm * 64 + i * 16 + l16;
                af[i] = *(const bf16x8*)(As + r * 64 + ((((ks << 2) + quad)) ^ (r & 7)) * 8);
            }
#pragma unroll
            for (int j = 0; j < 4; ++j) {
                int r = wn * 64 + j * 16 + l16;
                bfr[j] = *(const bf16x8*)(Bs + r * 64 + ((((ks << 2) + quad)) ^ (r & 7)) * 8);
            }
#pragma unroll
            for (int i = 0; i < 4; ++i)
#pragma unroll
                for (int j = 0; j < 4; ++j)
                    acc[i][j] = MFMA16(af[i], bfr[j], acc[i][j]);
        }
    }

#pragma unroll
    for (int i = 0; i < 4; ++i)
#pragma unroll
        for (int j = 0; j < 4; ++j)
#pragma unroll
            for (int r = 0; r < 4; ++r) {
                int m = m0 + wm * 64 + i * 16 + quad * 4 + r;
                int n = n0 + wn * 64 + j * 16 + l16;
                float v = acc[i][j][r];
                if (EPI == 0) {
                    int which = n >> 9, hh = (n >> 6) & 7, d = n & 63;
                    int bb = m >> 13, nn = m & 8191;
                    Cb[(size_t)which * 8388608 +
                       ((size_t)(bb * 8 + hh) * 8192 + nn) * 64 + d] = (bf16)v;
                } else if (EPI == 1) {
                    size_t idx = (size_t)m * 512 + n;
                    Cf[idx] = v + res[idx];
                } else {
                    size_t idx = (size_t)m * 512 + n;
                    float rv = res[idx];
                    Cf[idx] = v + rv + bias[n];
                }
            }
}

// ---------------------------------------------------------------------------
// l2norm + qk scale + xPos rotary, in place on q/k [BH,8192,64].
// ---------------------------------------------------------------------------
__global__ __launch_bounds__(512) void rot_kernel(bf16* __restrict__ qb,
                                                  bf16* __restrict__ kb,
                                                  const float* __restrict__ qscale,
                                                  const float* __restrict__ kscale) {
    int pos = blockIdx.x;
    int b = pos >> 13, n = pos & 8191;
    int h = threadIdx.x >> 6;
    int d = threadIdx.x & 63;
    size_t idx = ((size_t)(b * 8 + h) * 8192 + n) * 64 + d;
    float qv = (float)qb[idx];
    float kv = (float)kb[idx];
    float sq = qv * qv, sk = kv * kv;
#pragma unroll
    for (int off = 1; off < 64; off <<= 1) {
        sq += __shfl_xor(sq, off, 64);
        sk += __shfl_xor(sk, off, 64);
    }
    qv = qv / fmaxf(sqrtf(sq), 1e-12f) * qscale[d];
    kv = kv / fmaxf(sqrtf(sk), 1e-12f) * kscale[d];
    int i2 = d & 31;
    float invf = powf(10000.0f, -(float)i2 / 32.0f);
    float th = (float)n * invf;
    float c = cosf(th), s = sinf(th);
    float sv = ((float)(2 * i2) + 25.6f) / 89.6f;
    float pw = ((float)n - 4096.0f) * (1.0f / 256.0f);
    float xs = powf(sv, pw);
    float qo = __shfl_xor(qv, 32, 64);
    float ko = __shfl_xor(kv, 32, 64);
    float rhq = (d < 32) ? -qo : qo;
    float rhk = (d < 32) ? -ko : ko;
    qb[idx] = (bf16)((qv * c + rhq * s) * xs);
    kb[idx] = (bf16)((kv * c + rhk * s) / xs);
}

// ---------------------------------------------------------------------------
// Local windowed attention (flash-style), window 512, lookback one window.
// ---------------------------------------------------------------------------
__global__ __launch_bounds__(256) void attn_kernel(const bf16* __restrict__ q,
                                                   const bf16* __restrict__ k,
                                                   const bf16* __restrict__ v,
                                                   bf16* __restrict__ o) {
    __shared__ __align__(16) bf16 Ks[128][72];
    __shared__ __align__(16) bf16 Vt[64][136];
    __shared__ __align__(16) bf16 Ps[4][16][136];
    const int tid  = threadIdx.x;
    const int wid  = tid >> 6;
    const int lane = tid & 63;
    const int quad = lane >> 4;
    const int l16  = lane & 15;
    const int bh   = blockIdx.y;
    const int q0   = blockIdx.x * 64;
    const size_t qbase = (size_t)bh * 8192;

    bf16x8 aq[2];
    {
        int qrow = q0 + wid * 16 + l16;
        const bf16* qp = q + (qbase + qrow) * 64 + quad * 8;
        aq[0] = *(const bf16x8*)qp;
        aq[1] = *(const bf16x8*)(qp + 32);
    }
    f32x4 z4 = {0.f, 0.f, 0.f, 0.f};
    f32x4 accO[4];
    float mrow[4], lrow[4];
#pragma unroll
    for (int r = 0; r < 4; ++r) {
        accO[r] = z4;
        mrow[r] = -__builtin_inff();
        lrow[r] = 0.f;
    }

    int klo = q0 - 512;
    if (klo < 0) klo = 0;
    for (int kc = klo; kc < q0 + 64; kc += 128) {
        __syncthreads();
#pragma unroll
        for (int p = 0; p < 4; ++p) {
            int c  = tid + (p << 8);
            int key = c >> 3;
            int d0 = (c & 7) << 3;
            int gk = kc + key;
            uint4 kvu = make_uint4(0, 0, 0, 0);
            uint4 vvu = make_uint4(0, 0, 0, 0);
            if (gk < 8192) {
                kvu = *(const uint4*)(k + (qbase + gk) * 64 + d0);
                vvu = *(const uint4*)(v + (qbase + gk) * 64 + d0);
            }
            *(uint4*)&Ks[key][d0] = kvu;
            union { uint4 u; bf16 h[8]; } tv;
            tv.u = vvu;
#pragma unroll
            for (int j = 0; j < 8; ++j) Vt[d0 + j][key] = tv.h[j];
        }
        __syncthreads();
        f32x4 s[8];
#pragma unroll
        for (int ns = 0; ns < 8; ++ns) {
            s[ns] = z4;
            bf16x8 b0 = *(const bf16x8*)&Ks[ns * 16 + l16][quad * 8];
            s[ns] = MFMA16(aq[0], b0, s[ns]);
            bf16x8 b1 = *(const bf16x8*)&Ks[ns * 16 + l16][32 + quad * 8];
            s[ns] = MFMA16(aq[1], b1, s[ns]);
        }
        float mx[4] = {-__builtin_inff(), -__builtin_inff(),
                       -__builtin_inff(), -__builtin_inff()};
#pragma unroll
        for (int ns = 0; ns < 8; ++ns)
#pragma unroll
            for (int r = 0; r < 4; ++r) {
                int gi = q0 + wid * 16 + quad * 4 + r;
                int gj = kc + ns * 16 + l16;
                float sv = s[ns][r] * 8.0f;
                if (gj > gi || gj < gi - 512) sv = -__builtin_inff();
                s[ns][r] = sv;
                mx[r] = fmaxf(mx[r], sv);
            }
#pragma unroll
        for (int r = 0; r < 4; ++r) {
#pragma unroll
            for (int off = 1; off < 16; off <<= 1)
                mx[r] = fmaxf(mx[r], __shfl_xor(mx[r], off, 64));
        }
        float alpha[4], rs[4];
#pragma unroll
        for (int r = 0; r < 4; ++r) {
            float mn = fmaxf(mrow[r], mx[r]);
            alpha[r] = (mn == -__builtin_inff()) ? 1.0f : __expf(mrow[r] - mn);
            mrow[r] = mn;
            rs[r] = 0.f;
        }
#pragma unroll
        for (int ns = 0; ns < 8; ++ns)
#pragma unroll
            for (int r = 0; r < 4; ++r) {
                float pv = (s[ns][r] == -__builtin_inff())
                               ? 0.f
                               : __expf(s[ns][r] - mrow[r]);
                rs[r] += pv;
                Ps[wid][quad * 4 + r][ns * 16 + l16] = (bf16)pv;
            }
#pragma unroll
        for (int r = 0; r < 4; ++r) {
            float t = rs[r];
#pragma unroll
            for (int off = 1; off < 16; off <<= 1) t += __shfl_xor(t, off, 64);
            lrow[r] = lrow[r] * alpha[r] + t;
        }
#pragma unroll
        for (int ds = 0; ds < 4; ++ds)
#pragma unroll
            for (int r = 0; r < 4; ++r) accO[ds][r] *= alpha[r];
        __builtin_amdgcn_sched_barrier(0);  // keep P writes before P reads
#pragma unroll
        for (int ks2 = 0; ks2 < 4; ++ks2) {
            bf16x8 ap = *(const bf16x8*)&Ps[wid][l16][ks2 * 32 + quad * 8];
#pragma unroll
            for (int ds = 0; ds < 4; ++ds) {
                bf16x8 bv = *(const bf16x8*)&Vt[ds * 16 + l16][ks2 * 32 + quad * 8];
                accO[ds] = MFMA16(ap, bv, accO[ds]);
            }
        }
    }
    int bb = bh >> 3, hh = bh & 7;
#pragma unroll
    for (int ds = 0; ds < 4; ++ds)
#pragma unroll
        for (int r = 0; r < 4; ++r) {
            int m = q0 + wid * 16 + quad * 4 + r;
            float ov = accO[ds][r] / lrow[r];
            o[((size_t)(bb * 8192 + m)) * 512 + hh * 64 + ds * 16 + l16] = (bf16)ov;
        }
}

// ---------------------------------------------------------------------------
// FF1: fused dual-half (a + gate) GEMM + exact GELU, writes act [16384][1408]
// bf16 (cols >= 1365 zeroed). B from pre-transposed bf16 W1T [2816][512].
// ---------------------------------------------------------------------------
__global__ __launch_bounds__(256) void ff1_kernel(const bf16* __restrict__ A,
                                                  const bf16* __restrict__ W1T,
                                                  const float* __restrict__ b1,
                                                  bf16* __restrict__ act) {
    __shared__ __align__(16) bf16 As[128 * 64];
    __shared__ __align__(16) bf16 Bsa[64 * 64];
    __shared__ __align__(16) bf16 Bsg[64 * 64];
    const int tid  = threadIdx.x;
    const int wid  = tid >> 6;
    const int lane = tid & 63;
    const int quad = lane >> 4;
    const int l16  = lane & 15;
    const int wm   = wid >> 1;
    const int wn   = wid & 1;
    const int m0   = blockIdx.y * 128;
    const int n0   = blockIdx.x * 64;

    f32x4 z4 = {0.f, 0.f, 0.f, 0.f};
    f32x4 aa[4][2], ag[4][2];
#pragma unroll
    for (int i = 0; i < 4; ++i)
#pragma unroll
        for (int j = 0; j < 2; ++j) { aa[i][j] = z4; ag[i][j] = z4; }

    for (int kt = 0; kt < 512; kt += 64) {
        __syncthreads();
#pragma unroll
        for (int p = 0; p < 4; ++p) {
            int c   = tid + (p << 8);
            int row = c >> 3;
            int sl  = c & 7;
            int g   = sl ^ (row & 7);
            gld16(A + (size_t)(m0 + row) * 512 + kt + g * 8, As + c * 8);
        }
#pragma unroll
        for (int p = 0; p < 2; ++p) {
            int c   = tid + (p << 8);       // 0..511
            int row = c >> 3;               // 0..63
            int sl  = c & 7;
            int g   = sl ^ (row & 7);
            gld16(W1T + (size_t)(n0 + row) * 512 + kt + g * 8, Bsa + c * 8);
            gld16(W1T + (size_t)(1365 + n0 + row) * 512 + kt + g * 8, Bsg + c * 8);
        }
        __syncthreads();
#pragma unroll
        for (int ks = 0; ks < 2; ++ks) {
            bf16x8 af[4];
#pragma unroll
            for (int i = 0; i < 4; ++i) {
                int r = wm * 64 + i * 16 + l16;
                af[i] = *(const bf16x8*)(As + r * 64 + ((((ks << 2) + quad)) ^ (r & 7)) * 8);
            }
#pragma unroll
            for (int j = 0; j < 2; ++j) {
                int r = wn * 32 + j * 16 + l16;
                int sl = (((ks << 2) + quad)) ^ (r & 7);
                bf16x8 ba = *(const bf16x8*)(Bsa + r * 64 + sl * 8);
                bf16x8 bg = *(const bf16x8*)(Bsg + r * 64 + sl * 8);
#pragma unroll
                for (int i = 0; i < 4; ++i) {
                    aa[i][j] = MFMA16(af[i], ba, aa[i][j]);
                    ag[i][j] = MFMA16(af[i], bg, ag[i][j]);
                }
            }
        }
    }

#pragma unroll
    for (int i = 0; i < 4; ++i)
#pragma unroll
        for (int j = 0; j < 2; ++j)
#pragma unroll
            for (int r = 0; r < 4; ++r) {
                int m  = m0 + wm * 64 + i * 16 + quad * 4 + r;
                int n  = n0 + wn * 32 + j * 16 + l16;
                bf16 outv = (bf16)0.f;
                if (n < 1365) {
                    float av = aa[i][j][r] + b1[n];
                    float gv = ag[i][j][r] + b1[1365 + n];
                    float gel = 0.5f * gv * (1.0f + erff(gv * 0.70710678118f));
                    outv = (bf16)(av * gel);
                }
                act[(size_t)m * 1408 + n] = outv;
            }
}

// ---------------------------------------------------------------------------
// Launch
// ---------------------------------------------------------------------------
extern "C" void kernel_launch(void* const* d_in, const int* in_sizes, int n_in,
                              void* d_out, int out_size, void* d_ws, size_t ws_size,
                              hipStream_t stream) {
    const float* x      = (const float*)d_in[0];
    const float* ln1g   = (const float*)d_in[1];
    const float* ln1b   = (const float*)d_in[2];
    const float* Wqkv   = (const float*)d_in[3];
    const float* qscale = (const float*)d_in[4];
    const float* kscale = (const float*)d_in[5];
    const float* Wout   = (const float*)d_in[6];
    const float* ln2g   = (const float*)d_in[7];
    const float* ln2b   = (const float*)d_in[8];
    const float* W1     = (const float*)d_in[9];
    const float* b1     = (const float*)d_in[10];
    const float* W2     = (const float*)d_in[11];
    const float* b2     = (const float*)d_in[12];
    float* out = (float*)d_out;

    char* ws = (char*)d_ws;
    const size_t MB = 1024 * 1024;
    bf16* h   = (bf16*)(ws);             // 16 MB (reused: attn out o, then h2)
    bf16* qb  = (bf16*)(ws + 16 * MB);   // q/k/v contiguous 16..64 MB
    bf16* kb  = (bf16*)(ws + 32 * MB);
    bf16* vb  = (bf16*)(ws + 48 * MB);
    bf16* wts = (bf16*)(ws + 64 * MB);   // bf16 transposed weights, ~6.2 MB
    bf16* WqkvT = wts;                   // [1536][512]
    bf16* WoutT = WqkvT + 1536 * 512;    // [512][512]
    bf16* W1T   = WoutT + 512 * 512;     // [2816][512] (rows >=2730 zero)
    bf16* W2T   = W1T + 2816 * 512;      // [512][1408] (cols >=1365 zero)
    bf16* ob  = h;
    bf16* h2  = h;
    bf16* act = qb;                      // 46.2 MB over dead q/k/v
    float* x1 = out;                     // pre-FF residual lives in d_out

    // 0. weight prep (fp32 [K][N] -> bf16 [N][Kpad])
    tcvt_kernel<<<dim3(16, 48), dim3(32, 8), 0, stream>>>(Wqkv, WqkvT, 512, 1536, 512, 1536);
    tcvt_kernel<<<dim3(16, 16), dim3(32, 8), 0, stream>>>(Wout, WoutT, 512, 512, 512, 512);
    tcvt_kernel<<<dim3(16, 88), dim3(32, 8), 0, stream>>>(W1, W1T, 512, 2730, 512, 2816);
    tcvt_kernel<<<dim3(44, 16), dim3(32, 8), 0, stream>>>(W2, W2T, 1365, 512, 1408, 512);
    // 1. LN1
    ln_kernel<<<4096, 256, 0, stream>>>(x, ln1g, ln1b, h);
    // 2. QKV GEMM -> per-head q/k/v
    gemm_bt<0><<<dim3(12, 128), 256, 0, stream>>>(h, WqkvT, 512, qb, nullptr, nullptr, nullptr);
    // 3. l2norm + scale + rotary (in place)
    rot_kernel<<<16384, 512, 0, stream>>>(qb, kb, qscale, kscale);
    // 4. local attention
    attn_kernel<<<dim3(128, 16), 256, 0, stream>>>(qb, kb, vb, ob);
    // 5. out-proj + residual -> x1 (d_out, fp32)
    gemm_bt<1><<<dim3(4, 128), 256, 0, stream>>>(ob, WoutT, 512, nullptr, x1, x, nullptr);
    // 6. LN2 (reads d_out)
    ln_kernel<<<4096, 256, 0, stream>>>(x1, ln2g, ln2b, h2);
    // 7. FF1 fused dual-half + exact gelu -> act
    ff1_kernel<<<dim3(22, 128), 256, 0, stream>>>(h2, W1T, b1, act);
    // 8. FF2 + b2 + residual (in-place on d_out)
    gemm_bt<2><<<dim3(4, 128), 256, 0, stream>>>(act, W2T, 1408, nullptr, out, x1, b2);
}

// Round 3
// 489.746 us; speedup vs baseline: 2.2143x; 1.0219x over previous
//
#include <hip/hip_runtime.h>
#include <cstdint>
#include <cstddef>

typedef __bf16 bf16;
typedef __bf16 bf16x8 __attribute__((ext_vector_type(8)));
typedef float  f32x4  __attribute__((ext_vector_type(4)));

#define MFMA16(a, b, c) __builtin_amdgcn_mfma_f32_16x16x32_bf16((a), (b), (c), 0, 0, 0)

// async global->LDS, 16B per lane; data lands at wave-uniform base + lane*16
static __device__ __forceinline__ void gld16(const bf16* g, bf16* l) {
    __builtin_amdgcn_global_load_lds(
        (const __attribute__((address_space(1))) void*)g,
        (__attribute__((address_space(3))) void*)l, 16, 0, 0);
}

static __device__ __forceinline__ unsigned pack_bf16x2(bf16 a, bf16 b) {
    union { unsigned u; bf16 h[2]; } t;
    t.h[0] = a; t.h[1] = b;
    return t.u;
}

// ---------------------------------------------------------------------------
// Weight prep: fp32 [K][N] -> bf16 [Nrows][Kpad] (transposed, zero-padded)
// ---------------------------------------------------------------------------
__global__ __launch_bounds__(256) void tcvt_kernel(const float* __restrict__ src,
                                                   bf16* __restrict__ dst,
                                                   int K, int N, int Kpad, int Nrows) {
    __shared__ float t[32][33];
    int k0 = blockIdx.x * 32, n0 = blockIdx.y * 32;
#pragma unroll
    for (int i = threadIdx.y; i < 32; i += 8) {
        int k = k0 + i, n = n0 + threadIdx.x;
        t[i][threadIdx.x] = (k < K && n < N) ? src[(size_t)k * N + n] : 0.f;
    }
    __syncthreads();
#pragma unroll
    for (int i = threadIdx.y; i < 32; i += 8) {
        int n = n0 + i, k = k0 + threadIdx.x;
        if (n < Nrows && k < Kpad) dst[(size_t)n * Kpad + k] = (bf16)t[threadIdx.x][i];
    }
}

// ---------------------------------------------------------------------------
// LayerNorm: one wave per 512-element row, fp32 in, bf16 out
// ---------------------------------------------------------------------------
__global__ __launch_bounds__(256) void ln_kernel(const float* __restrict__ x,
                                                 const float* __restrict__ g,
                                                 const float* __restrict__ b,
                                                 bf16* __restrict__ out) {
    int row  = blockIdx.x * 4 + (threadIdx.x >> 6);
    int lane = threadIdx.x & 63;
    const float* xr = x + (size_t)row * 512 + lane * 8;
    float4 v0 = *(const float4*)xr;
    float4 v1 = *(const float4*)(xr + 4);
    float s  = v0.x + v0.y + v0.z + v0.w + v1.x + v1.y + v1.z + v1.w;
    float ss = v0.x*v0.x + v0.y*v0.y + v0.z*v0.z + v0.w*v0.w
             + v1.x*v1.x + v1.y*v1.y + v1.z*v1.z + v1.w*v1.w;
#pragma unroll
    for (int off = 1; off < 64; off <<= 1) {
        s  += __shfl_xor(s, off, 64);
        ss += __shfl_xor(ss, off, 64);
    }
    float mean = s * (1.0f / 512.0f);
    float var  = ss * (1.0f / 512.0f) - mean * mean;
    float rstd = rsqrtf(var + 1e-5f);
    const float* gr = g + lane * 8;
    const float* br = b + lane * 8;
    float4 g0 = *(const float4*)gr, g1 = *(const float4*)(gr + 4);
    float4 b0 = *(const float4*)br, b1 = *(const float4*)(br + 4);
    bf16x8 o;
    o[0] = (bf16)((v0.x - mean) * rstd * g0.x + b0.x);
    o[1] = (bf16)((v0.y - mean) * rstd * g0.y + b0.y);
    o[2] = (bf16)((v0.z - mean) * rstd * g0.z + b0.z);
    o[3] = (bf16)((v0.w - mean) * rstd * g0.w + b0.w);
    o[4] = (bf16)((v1.x - mean) * rstd * g1.x + b1.x);
    o[5] = (bf16)((v1.y - mean) * rstd * g1.y + b1.y);
    o[6] = (bf16)((v1.z - mean) * rstd * g1.z + b1.z);
    o[7] = (bf16)((v1.w - mean) * rstd * g1.w + b1.w);
    *(uint4*)(out + (size_t)row * 512 + lane * 8) = *(uint4*)&o;
}

// ---------------------------------------------------------------------------
// m97-style bf16 GEMM: A [M][K], B [N][K] (pre-transposed bf16 weights).
// ---------------------------------------------------------------------------
template <int EPI>
__global__ __launch_bounds__(256) void gemm_bt(
    const bf16* __restrict__ A, const bf16* __restrict__ Bm, int K,
    bf16* __restrict__ Cb, float* Cf,
    const float* res, const float* __restrict__ bias) {
    __shared__ __align__(16) bf16 As[128 * 64];
    __shared__ __align__(16) bf16 Bs[128 * 64];
    const int tid  = threadIdx.x;
    const int wid  = tid >> 6;
    const int lane = tid & 63;
    const int quad = lane >> 4;
    const int l16  = lane & 15;
    const int wm   = wid >> 1;
    const int wn   = wid & 1;
    const int m0   = blockIdx.y * 128;
    const int n0   = blockIdx.x * 128;

    f32x4 z4 = {0.f, 0.f, 0.f, 0.f};
    f32x4 acc[4][4];
#pragma unroll
    for (int i = 0; i < 4; ++i)
#pragma unroll
        for (int j = 0; j < 4; ++j) acc[i][j] = z4;

    for (int kt = 0; kt < K; kt += 64) {
        __syncthreads();
#pragma unroll
        for (int p = 0; p < 4; ++p) {
            int c   = tid + (p << 8);
            int row = c >> 3;
            int sl  = c & 7;
            int g   = sl ^ (row & 7);
            gld16(A  + (size_t)(m0 + row) * K + kt + g * 8, As + c * 8);
            gld16(Bm + (size_t)(n0 + row) * K + kt + g * 8, Bs + c * 8);
        }
        __syncthreads();
#pragma unroll
        for (int ks = 0; ks < 2; ++ks) {
            bf16x8 af[4], bfr[4];
#pragma unroll
            for (int i = 0; i < 4; ++i) {
                int r = wm * 64 + i * 16 + l16;
                af[i] = *(const bf16x8*)(As + r * 64 + ((((ks << 2) + quad)) ^ (r & 7)) * 8);
            }
#pragma unroll
            for (int j = 0; j < 4; ++j) {
                int r = wn * 64 + j * 16 + l16;
                bfr[j] = *(const bf16x8*)(Bs + r * 64 + ((((ks << 2) + quad)) ^ (r & 7)) * 8);
            }
#pragma unroll
            for (int i = 0; i < 4; ++i)
#pragma unroll
                for (int j = 0; j < 4; ++j)
                    acc[i][j] = MFMA16(af[i], bfr[j], acc[i][j]);
        }
    }

#pragma unroll
    for (int i = 0; i < 4; ++i)
#pragma unroll
        for (int j = 0; j < 4; ++j)
#pragma unroll
            for (int r = 0; r < 4; ++r) {
                int m = m0 + wm * 64 + i * 16 + quad * 4 + r;
                int n = n0 + wn * 64 + j * 16 + l16;
                float v = acc[i][j][r];
                if (EPI == 0) {
                    int which = n >> 9, hh = (n >> 6) & 7, d = n & 63;
                    int bb = m >> 13, nn = m & 8191;
                    Cb[(size_t)which * 8388608 +
                       ((size_t)(bb * 8 + hh) * 8192 + nn) * 64 + d] = (bf16)v;
                } else if (EPI == 1) {
                    size_t idx = (size_t)m * 512 + n;
                    Cf[idx] = v + res[idx];
                } else {
                    size_t idx = (size_t)m * 512 + n;
                    float rv = res[idx];
                    Cf[idx] = v + rv + bias[n];
                }
            }
}

// ---------------------------------------------------------------------------
// l2norm + qk scale + xPos rotary, in place on q/k [BH,8192,64].
// ---------------------------------------------------------------------------
__global__ __launch_bounds__(512) void rot_kernel(bf16* __restrict__ qb,
                                                  bf16* __restrict__ kb,
                                                  const float* __restrict__ qscale,
                                                  const float* __restrict__ kscale) {
    int pos = blockIdx.x;
    int b = pos >> 13, n = pos & 8191;
    int h = threadIdx.x >> 6;
    int d = threadIdx.x & 63;
    size_t idx = ((size_t)(b * 8 + h) * 8192 + n) * 64 + d;
    float qv = (float)qb[idx];
    float kv = (float)kb[idx];
    float sq = qv * qv, sk = kv * kv;
#pragma unroll
    for (int off = 1; off < 64; off <<= 1) {
        sq += __shfl_xor(sq, off, 64);
        sk += __shfl_xor(sk, off, 64);
    }
    qv = qv / fmaxf(sqrtf(sq), 1e-12f) * qscale[d];
    kv = kv / fmaxf(sqrtf(sk), 1e-12f) * kscale[d];
    int i2 = d & 31;
    float invf = powf(10000.0f, -(float)i2 / 32.0f);
    float th = (float)n * invf;
    float c = cosf(th), s = sinf(th);
    float sv = ((float)(2 * i2) + 25.6f) / 89.6f;
    float pw = ((float)n - 4096.0f) * (1.0f / 256.0f);
    float xs = powf(sv, pw);
    float qo = __shfl_xor(qv, 32, 64);
    float ko = __shfl_xor(kv, 32, 64);
    float rhq = (d < 32) ? -qo : qo;
    float rhk = (d < 32) ? -ko : ko;
    qb[idx] = (bf16)((qv * c + rhq * s) * xs);
    kb[idx] = (bf16)((kv * c + rhk * s) / xs);
}

// ---------------------------------------------------------------------------
// Local windowed attention, fixed-max softmax (|s| <= 8 by construction:
// q,k l2-normalized and the xPos decay factor is <=1 for all unmasked (i,j)).
// Block = 128 q-rows, wave = 32 rows (2 m-tiles). K/V chunks of 128 in LDS.
// K staged async (global_load_lds, XOR swizzle); V transposed via paired-key
// packed-b32 writes (bank = (4j+kp) mod 32 -> 2-way, free).
// ---------------------------------------------------------------------------
__global__ __launch_bounds__(256) void attn_kernel(const bf16* __restrict__ q,
                                                   const bf16* __restrict__ k,
                                                   const bf16* __restrict__ v,
                                                   bf16* __restrict__ o) {
    __shared__ __align__(16) bf16 Ks[128 * 64];
    __shared__ __align__(16) bf16 Vt[64][136];
    __shared__ __align__(16) bf16 Ps[4][16][136];
    const int tid  = threadIdx.x;
    const int wid  = tid >> 6;
    const int lane = tid & 63;
    const int quad = lane >> 4;
    const int l16  = lane & 15;
    // XCD swizzle: adjacent q-tiles of one bh land on the same XCD
    const int lid = (blockIdx.x & 7) * 128 + (blockIdx.x >> 3);
    const int bh  = lid >> 6;
    const int q0  = (lid & 63) * 128;
    const size_t base = (size_t)bh * 8192;

    // Q fragments: 2 m-tiles x 2 k-halves
    bf16x8 aq[2][2];
#pragma unroll
    for (int mt = 0; mt < 2; ++mt) {
        int qrow = q0 + wid * 32 + mt * 16 + l16;
        const bf16* qp = q + (base + qrow) * 64 + quad * 8;
        aq[mt][0] = *(const bf16x8*)qp;
        aq[mt][1] = *(const bf16x8*)(qp + 32);
    }
    f32x4 z4 = {0.f, 0.f, 0.f, 0.f};
    f32x4 accO[2][4];
    float rs[2][4];
#pragma unroll
    for (int mt = 0; mt < 2; ++mt)
#pragma unroll
        for (int j = 0; j < 4; ++j) { accO[mt][j] = z4; rs[mt][j] = 0.f; }

    int klo = q0 - 512;
    if (klo < 0) klo = 0;
    for (int kc = klo; kc < q0 + 128; kc += 128) {
        __syncthreads();
        // K: async staging, XOR-swizzled 16B chunks (all keys in-bounds)
#pragma unroll
        for (int p = 0; p < 4; ++p) {
            int c   = tid + (p << 8);
            int row = c >> 3;
            int g   = (c & 7) ^ (row & 7);
            gld16(k + (base + kc + row) * 64 + g * 8, Ks + c * 8);
        }
        // V: transpose stage. Thread: key pair 2*lane, d-chunks {2wid, 2wid+1}.
        {
            int kp = lane;
#pragma unroll
            for (int w2 = 0; w2 < 2; ++w2) {
                int dc = wid * 2 + w2;
                const bf16* vp = v + (base + kc + kp * 2) * 64 + dc * 8;
                union { uint4 u; bf16 h[8]; } va, vb2;
                va.u  = *(const uint4*)vp;
                vb2.u = *(const uint4*)(vp + 64);
#pragma unroll
                for (int j = 0; j < 8; ++j)
                    *(unsigned*)&Vt[dc * 8 + j][kp * 2] =
                        pack_bf16x2(va.h[j], vb2.h[j]);
            }
        }
        __syncthreads();
#pragma unroll
        for (int mt = 0; mt < 2; ++mt) {
            // S = Q K^T: 16 rows x 128 keys
            f32x4 s[8];
#pragma unroll
            for (int ns = 0; ns < 8; ++ns) {
                int row = ns * 16 + l16;
                bf16x8 b0 = *(const bf16x8*)(Ks + row * 64 + ((quad    ) ^ (row & 7)) * 8);
                bf16x8 b1 = *(const bf16x8*)(Ks + row * 64 + ((4 + quad) ^ (row & 7)) * 8);
                f32x4 t = z4;
                t = MFMA16(aq[mt][0], b0, t);
                t = MFMA16(aq[mt][1], b1, t);
                s[ns] = t;
            }
            // p = exp2(11.54156*s - 11.54156) = exp(8s - 8), masked; write P
            int gi0 = q0 + wid * 32 + mt * 16 + quad * 4;
#pragma unroll
            for (int ns = 0; ns < 8; ++ns) {
                int gj = kc + ns * 16 + l16;
#pragma unroll
                for (int r = 0; r < 4; ++r) {
                    int e = gi0 + r - gj;  // valid iff 0 <= e <= 512
                    float p = __builtin_exp2f(
                        fmaf(s[ns][r], 11.541560327f, -11.541560327f));
                    p = ((unsigned)e <= 512u) ? p : 0.f;
                    rs[mt][r] += p;
                    Ps[wid][quad * 4 + r][ns * 16 + l16] = (bf16)p;
                }
            }
            // O[mt] += P V  (wave-private Ps; waitcnt ordering, no barrier)
#pragma unroll
            for (int ks2 = 0; ks2 < 4; ++ks2) {
                bf16x8 ap = *(const bf16x8*)&Ps[wid][l16][ks2 * 32 + quad * 8];
#pragma unroll
                for (int ds = 0; ds < 4; ++ds) {
                    bf16x8 bv = *(const bf16x8*)&Vt[ds * 16 + l16][ks2 * 32 + quad * 8];
                    accO[mt][ds] = MFMA16(ap, bv, accO[mt][ds]);
                }
            }
        }
    }
    // row-sum reduce over the 16 lanes (l16) sharing each row, then store
#pragma unroll
    for (int mt = 0; mt < 2; ++mt)
#pragma unroll
        for (int r = 0; r < 4; ++r) {
            float t = rs[mt][r];
            t += __shfl_xor(t, 1, 64);
            t += __shfl_xor(t, 2, 64);
            t += __shfl_xor(t, 4, 64);
            t += __shfl_xor(t, 8, 64);
            rs[mt][r] = 1.0f / t;
        }
    int bb = bh >> 3, hh = bh & 7;
#pragma unroll
    for (int mt = 0; mt < 2; ++mt)
#pragma unroll
        for (int ds = 0; ds < 4; ++ds)
#pragma unroll
            for (int r = 0; r < 4; ++r) {
                int m = q0 + wid * 32 + mt * 16 + quad * 4 + r;
                o[((size_t)(bb * 8192 + m)) * 512 + hh * 64 + ds * 16 + l16] =
                    (bf16)(accO[mt][ds][r] * rs[mt][r]);
            }
}

// ---------------------------------------------------------------------------
// FF1: fused dual-half (a + gate) GEMM + exact GELU -> act [16384][1408] bf16
// ---------------------------------------------------------------------------
__global__ __launch_bounds__(256) void ff1_kernel(const bf16* __restrict__ A,
                                                  const bf16* __restrict__ W1T,
                                                  const float* __restrict__ b1,
                                                  bf16* __restrict__ act) {
    __shared__ __align__(16) bf16 As[128 * 64];
    __shared__ __align__(16) bf16 Bsa[64 * 64];
    __shared__ __align__(16) bf16 Bsg[64 * 64];
    const int tid  = threadIdx.x;
    const int wid  = tid >> 6;
    const int lane = tid & 63;
    const int quad = lane >> 4;
    const int l16  = lane & 15;
    const int wm   = wid >> 1;
    const int wn   = wid & 1;
    const int m0   = blockIdx.y * 128;
    const int n0   = blockIdx.x * 64;

    f32x4 z4 = {0.f, 0.f, 0.f, 0.f};
    f32x4 aa[4][2], ag[4][2];
#pragma unroll
    for (int i = 0; i < 4; ++i)
#pragma unroll
        for (int j = 0; j < 2; ++j) { aa[i][j] = z4; ag[i][j] = z4; }

    for (int kt = 0; kt < 512; kt += 64) {
        __syncthreads();
#pragma unroll
        for (int p = 0; p < 4; ++p) {
            int c   = tid + (p << 8);
            int row = c >> 3;
            int g   = (c & 7) ^ (row & 7);
            gld16(A + (size_t)(m0 + row) * 512 + kt + g * 8, As + c * 8);
        }
#pragma unroll
        for (int p = 0; p < 2; ++p) {
            int c   = tid + (p << 8);
            int row = c >> 3;
            int g   = (c & 7) ^ (row & 7);
            gld16(W1T + (size_t)(n0 + row) * 512 + kt + g * 8, Bsa + c * 8);
            gld16(W1T + (size_t)(1365 + n0 + row) * 512 + kt + g * 8, Bsg + c * 8);
        }
        __syncthreads();
#pragma unroll
        for (int ks = 0; ks < 2; ++ks) {
            bf16x8 af[4];
#pragma unroll
            for (int i = 0; i < 4; ++i) {
                int r = wm * 64 + i * 16 + l16;
                af[i] = *(const bf16x8*)(As + r * 64 + ((((ks << 2) + quad)) ^ (r & 7)) * 8);
            }
#pragma unroll
            for (int j = 0; j < 2; ++j) {
                int r = wn * 32 + j * 16 + l16;
                int sl = (((ks << 2) + quad)) ^ (r & 7);
                bf16x8 ba = *(const bf16x8*)(Bsa + r * 64 + sl * 8);
                bf16x8 bg = *(const bf16x8*)(Bsg + r * 64 + sl * 8);
#pragma unroll
                for (int i = 0; i < 4; ++i) {
                    aa[i][j] = MFMA16(af[i], ba, aa[i][j]);
                    ag[i][j] = MFMA16(af[i], bg, ag[i][j]);
                }
            }
        }
    }

#pragma unroll
    for (int i = 0; i < 4; ++i)
#pragma unroll
        for (int j = 0; j < 2; ++j)
#pragma unroll
            for (int r = 0; r < 4; ++r) {
                int m  = m0 + wm * 64 + i * 16 + quad * 4 + r;
                int n  = n0 + wn * 32 + j * 16 + l16;
                bf16 outv = (bf16)0.f;
                if (n < 1365) {
                    float av = aa[i][j][r] + b1[n];
                    float gv = ag[i][j][r] + b1[1365 + n];
                    float gel = 0.5f * gv * (1.0f + erff(gv * 0.70710678118f));
                    outv = (bf16)(av * gel);
                }
                act[(size_t)m * 1408 + n] = outv;
            }
}

// ---------------------------------------------------------------------------
// Launch
// ---------------------------------------------------------------------------
extern "C" void kernel_launch(void* const* d_in, const int* in_sizes, int n_in,
                              void* d_out, int out_size, void* d_ws, size_t ws_size,
                              hipStream_t stream) {
    const float* x      = (const float*)d_in[0];
    const float* ln1g   = (const float*)d_in[1];
    const float* ln1b   = (const float*)d_in[2];
    const float* Wqkv   = (const float*)d_in[3];
    const float* qscale = (const float*)d_in[4];
    const float* kscale = (const float*)d_in[5];
    const float* Wout   = (const float*)d_in[6];
    const float* ln2g   = (const float*)d_in[7];
    const float* ln2b   = (const float*)d_in[8];
    const float* W1     = (const float*)d_in[9];
    const float* b1     = (const float*)d_in[10];
    const float* W2     = (const float*)d_in[11];
    const float* b2     = (const float*)d_in[12];
    float* out = (float*)d_out;

    char* ws = (char*)d_ws;
    const size_t MB = 1024 * 1024;
    bf16* h   = (bf16*)(ws);             // 16 MB (reused: attn out o, then h2)
    bf16* qb  = (bf16*)(ws + 16 * MB);   // q/k/v contiguous 16..64 MB
    bf16* kb  = (bf16*)(ws + 32 * MB);
    bf16* vb  = (bf16*)(ws + 48 * MB);
    bf16* wts = (bf16*)(ws + 64 * MB);   // bf16 transposed weights, ~6.2 MB
    bf16* WqkvT = wts;                   // [1536][512]
    bf16* WoutT = WqkvT + 1536 * 512;    // [512][512]
    bf16* W1T   = WoutT + 512 * 512;     // [2816][512] (rows >=2730 zero)
    bf16* W2T   = W1T + 2816 * 512;      // [512][1408] (cols >=1365 zero)
    bf16* ob  = h;
    bf16* h2  = h;
    bf16* act = qb;                      // 46.2 MB over dead q/k/v
    float* x1 = out;                     // pre-FF residual lives in d_out

    // 0. weight prep (fp32 [K][N] -> bf16 [N][Kpad])
    tcvt_kernel<<<dim3(16, 48), dim3(32, 8), 0, stream>>>(Wqkv, WqkvT, 512, 1536, 512, 1536);
    tcvt_kernel<<<dim3(16, 16), dim3(32, 8), 0, stream>>>(Wout, WoutT, 512, 512, 512, 512);
    tcvt_kernel<<<dim3(16, 88), dim3(32, 8), 0, stream>>>(W1, W1T, 512, 2730, 512, 2816);
    tcvt_kernel<<<dim3(44, 16), dim3(32, 8), 0, stream>>>(W2, W2T, 1365, 512, 1408, 512);
    // 1. LN1
    ln_kernel<<<4096, 256, 0, stream>>>(x, ln1g, ln1b, h);
    // 2. QKV GEMM -> per-head q/k/v
    gemm_bt<0><<<dim3(12, 128), 256, 0, stream>>>(h, WqkvT, 512, qb, nullptr, nullptr, nullptr);
    // 3. l2norm + scale + rotary (in place)
    rot_kernel<<<16384, 512, 0, stream>>>(qb, kb, qscale, kscale);
    // 4. local attention (128-row q-tiles, XCD-swizzled flat grid)
    attn_kernel<<<1024, 256, 0, stream>>>(qb, kb, vb, ob);
    // 5. out-proj + residual -> x1 (d_out, fp32)
    gemm_bt<1><<<dim3(4, 128), 256, 0, stream>>>(ob, WoutT, 512, nullptr, x1, x, nullptr);
    // 6. LN2 (reads d_out)
    ln_kernel<<<4096, 256, 0, stream>>>(x1, ln2g, ln2b, h2);
    // 7. FF1 fused dual-half + exact gelu -> act
    ff1_kernel<<<dim3(22, 128), 256, 0, stream>>>(h2, W1T, b1, act);
    // 8. FF2 + b2 + residual (in-place on d_out)
    gemm_bt<2><<<dim3(4, 128), 256, 0, stream>>>(act, W2T, 1408, nullptr, out, x1, b2);
}

// Round 4
// 381.544 us; speedup vs baseline: 2.8423x; 1.2836x over previous
//
#include <hip/hip_runtime.h>
#include <cstdint>
#include <cstddef>

typedef __bf16 bf16;
typedef __bf16 bf16x8 __attribute__((ext_vector_type(8)));
typedef float  f32x4  __attribute__((ext_vector_type(4)));

#define MFMA16(a, b, c) __builtin_amdgcn_mfma_f32_16x16x32_bf16((a), (b), (c), 0, 0, 0)

// async global->LDS, 16B per lane; data lands at wave-uniform base + lane*16
static __device__ __forceinline__ void gld16(const bf16* g, bf16* l) {
    __builtin_amdgcn_global_load_lds(
        (const __attribute__((address_space(1))) void*)g,
        (__attribute__((address_space(3))) void*)l, 16, 0, 0);
}

static __device__ __forceinline__ unsigned pack_bf16x2(bf16 a, bf16 b) {
    union { unsigned u; bf16 h[2]; } t;
    t.h[0] = a; t.h[1] = b;
    return t.u;
}

// ---------------------------------------------------------------------------
// Weight prep: fp32 [K][N] -> bf16 [Nrows][Kpad] (transposed, zero-padded)
// ---------------------------------------------------------------------------
__global__ __launch_bounds__(256) void tcvt_kernel(const float* __restrict__ src,
                                                   bf16* __restrict__ dst,
                                                   int K, int N, int Kpad, int Nrows) {
    __shared__ float t[32][33];
    int k0 = blockIdx.x * 32, n0 = blockIdx.y * 32;
#pragma unroll
    for (int i = threadIdx.y; i < 32; i += 8) {
        int k = k0 + i, n = n0 + threadIdx.x;
        t[i][threadIdx.x] = (k < K && n < N) ? src[(size_t)k * N + n] : 0.f;
    }
    __syncthreads();
#pragma unroll
    for (int i = threadIdx.y; i < 32; i += 8) {
        int n = n0 + i, k = k0 + threadIdx.x;
        if (n < Nrows && k < Kpad) dst[(size_t)n * Kpad + k] = (bf16)t[threadIdx.x][i];
    }
}

// ---------------------------------------------------------------------------
// LayerNorm: one wave per 512-element row, fp32 in, bf16 out
// ---------------------------------------------------------------------------
__global__ __launch_bounds__(256) void ln_kernel(const float* __restrict__ x,
                                                 const float* __restrict__ g,
                                                 const float* __restrict__ b,
                                                 bf16* __restrict__ out) {
    int row  = blockIdx.x * 4 + (threadIdx.x >> 6);
    int lane = threadIdx.x & 63;
    const float* xr = x + (size_t)row * 512 + lane * 8;
    float4 v0 = *(const float4*)xr;
    float4 v1 = *(const float4*)(xr + 4);
    float s  = v0.x + v0.y + v0.z + v0.w + v1.x + v1.y + v1.z + v1.w;
    float ss = v0.x*v0.x + v0.y*v0.y + v0.z*v0.z + v0.w*v0.w
             + v1.x*v1.x + v1.y*v1.y + v1.z*v1.z + v1.w*v1.w;
#pragma unroll
    for (int off = 1; off < 64; off <<= 1) {
        s  += __shfl_xor(s, off, 64);
        ss += __shfl_xor(ss, off, 64);
    }
    float mean = s * (1.0f / 512.0f);
    float var  = ss * (1.0f / 512.0f) - mean * mean;
    float rstd = rsqrtf(var + 1e-5f);
    const float* gr = g + lane * 8;
    const float* br = b + lane * 8;
    float4 g0 = *(const float4*)gr, g1 = *(const float4*)(gr + 4);
    float4 b0 = *(const float4*)br, b1 = *(const float4*)(br + 4);
    bf16x8 o;
    o[0] = (bf16)((v0.x - mean) * rstd * g0.x + b0.x);
    o[1] = (bf16)((v0.y - mean) * rstd * g0.y + b0.y);
    o[2] = (bf16)((v0.z - mean) * rstd * g0.z + b0.z);
    o[3] = (bf16)((v0.w - mean) * rstd * g0.w + b0.w);
    o[4] = (bf16)((v1.x - mean) * rstd * g1.x + b1.x);
    o[5] = (bf16)((v1.y - mean) * rstd * g1.y + b1.y);
    o[6] = (bf16)((v1.z - mean) * rstd * g1.z + b1.z);
    o[7] = (bf16)((v1.w - mean) * rstd * g1.w + b1.w);
    *(uint4*)(out + (size_t)row * 512 + lane * 8) = *(uint4*)&o;
}

// ---------------------------------------------------------------------------
// m97-style bf16 GEMM: A [M][K], B [N][K] (pre-transposed bf16 weights).
// EPI 0: fused l2norm + qk-scale + xPos rotary epilogue, scatter to
//        q/k/v [3][BH][8192][64] bf16 (res=qscale, bias=kscale).
// EPI 1: Cf = acc + res            (out-proj + residual)
// EPI 2: Cf = acc + res + bias[n]  (ff2 + bias + residual, in-place on d_out)
// ---------------------------------------------------------------------------
template <int EPI>
__global__ __launch_bounds__(256) void gemm_bt(
    const bf16* __restrict__ A, const bf16* __restrict__ Bm, int K,
    bf16* __restrict__ Cb, float* Cf,
    const float* res, const float* __restrict__ bias) {
    __shared__ __align__(16) bf16 As[128 * 64];
    __shared__ __align__(16) bf16 Bs[128 * 64];
    const int tid  = threadIdx.x;
    const int wid  = tid >> 6;
    const int lane = tid & 63;
    const int quad = lane >> 4;
    const int l16  = lane & 15;
    const int wm   = wid >> 1;
    const int wn   = wid & 1;
    const int m0   = blockIdx.y * 128;
    const int n0   = blockIdx.x * 128;

    f32x4 z4 = {0.f, 0.f, 0.f, 0.f};
    f32x4 acc[4][4];
#pragma unroll
    for (int i = 0; i < 4; ++i)
#pragma unroll
        for (int j = 0; j < 4; ++j) acc[i][j] = z4;

    for (int kt = 0; kt < K; kt += 64) {
        __syncthreads();
#pragma unroll
        for (int p = 0; p < 4; ++p) {
            int c   = tid + (p << 8);
            int row = c >> 3;
            int sl  = c & 7;
            int g   = sl ^ (row & 7);
            gld16(A  + (size_t)(m0 + row) * K + kt + g * 8, As + c * 8);
            gld16(Bm + (size_t)(n0 + row) * K + kt + g * 8, Bs + c * 8);
        }
        __syncthreads();
#pragma unroll
        for (int ks = 0; ks < 2; ++ks) {
            bf16x8 af[4], bfr[4];
#pragma unroll
            for (int i = 0; i < 4; ++i) {
                int r = wm * 64 + i * 16 + l16;
                af[i] = *(const bf16x8*)(As + r * 64 + ((((ks << 2) + quad)) ^ (r & 7)) * 8);
            }
#pragma unroll
            for (int j = 0; j < 4; ++j) {
                int r = wn * 64 + j * 16 + l16;
                bfr[j] = *(const bf16x8*)(Bs + r * 64 + ((((ks << 2) + quad)) ^ (r & 7)) * 8);
            }
#pragma unroll
            for (int i = 0; i < 4; ++i)
#pragma unroll
                for (int j = 0; j < 4; ++j)
                    acc[i][j] = MFMA16(af[i], bfr[j], acc[i][j]);
        }
    }

    if (EPI == 0) {
        // Wave-uniform section: n-range [nbase, nbase+64) is head-aligned.
        const int nbase = n0 + wn * 64;
        const int which = nbase >> 9;     // 0=q, 1=k, 2=v
        const int hh    = (nbase >> 6) & 7;
        if (which == 2) {
#pragma unroll
            for (int i = 0; i < 4; ++i)
#pragma unroll
                for (int j = 0; j < 4; ++j)
#pragma unroll
                    for (int r = 0; r < 4; ++r) {
                        int m = m0 + wm * 64 + i * 16 + quad * 4 + r;
                        int d = j * 16 + l16;
                        int bb = m >> 13, nn = m & 8191;
                        Cb[(size_t)2 * 8388608 +
                           ((size_t)(bb * 8 + hh) * 8192 + nn) * 64 + d] =
                            (bf16)acc[i][j][r];
                    }
        } else {
            // l2norm + scale + xPos rotary, all in registers + DPP shuffles.
            const float* scale = (which == 0) ? res : bias;  // qscale / kscale
            const float sgn = (which == 0) ? 1.0f : -1.0f;   // xs vs 1/xs
            float sc[4], revf[4], lg[4];
#pragma unroll
            for (int j = 0; j < 4; ++j) {
                int d  = j * 16 + l16;
                int i2 = d & 31;
                sc[j]   = scale[d];
                // 10000^(-i2/32) / (2*pi)
                revf[j] = __builtin_exp2f(-(float)i2 * 0.4152410118609190f) *
                          0.15915494309189535f;
                lg[j]   = __builtin_log2f(((float)(2 * i2) + 25.6f) * (1.0f / 89.6f));
            }
            const size_t obase = (size_t)which * 8388608;
#pragma unroll
            for (int i = 0; i < 4; ++i)
#pragma unroll
                for (int r = 0; r < 4; ++r) {
                    int m = m0 + wm * 64 + i * 16 + quad * 4 + r;
                    int bb = m >> 13, nn = m & 8191;
                    float ss = 0.f;
#pragma unroll
                    for (int j = 0; j < 4; ++j) ss += acc[i][j][r] * acc[i][j][r];
                    ss += __shfl_xor(ss, 1, 64);
                    ss += __shfl_xor(ss, 2, 64);
                    ss += __shfl_xor(ss, 4, 64);
                    ss += __shfl_xor(ss, 8, 64);
                    float rn = rsqrtf(fmaxf(ss, 1e-24f));
                    float val[4];
#pragma unroll
                    for (int j = 0; j < 4; ++j) val[j] = acc[i][j][r] * rn * sc[j];
                    float fn = (float)nn;
                    float pw = (fn - 4096.0f) * (1.0f / 256.0f) * sgn;
#pragma unroll
                    for (int j = 0; j < 4; ++j) {
                        float xrev = fn * revf[j];
                        xrev -= floorf(xrev);
                        float cv = __builtin_amdgcn_cosf(xrev);
                        float sv = __builtin_amdgcn_sinf(xrev);
                        float xs = __builtin_exp2f(pw * lg[j]);
                        float rh = (j < 2) ? -val[j ^ 2] : val[j ^ 2];
                        float ov = (val[j] * cv + rh * sv) * xs;
                        int d = j * 16 + l16;
                        Cb[obase + ((size_t)(bb * 8 + hh) * 8192 + nn) * 64 + d] =
                            (bf16)ov;
                    }
                }
        }
    } else {
#pragma unroll
        for (int i = 0; i < 4; ++i)
#pragma unroll
            for (int j = 0; j < 4; ++j)
#pragma unroll
                for (int r = 0; r < 4; ++r) {
                    int m = m0 + wm * 64 + i * 16 + quad * 4 + r;
                    int n = n0 + wn * 64 + j * 16 + l16;
                    float v = acc[i][j][r];
                    size_t idx = (size_t)m * 512 + n;
                    if (EPI == 1) {
                        Cf[idx] = v + res[idx];
                    } else {
                        float rv = res[idx];
                        Cf[idx] = v + rv + bias[n];
                    }
                }
    }
}

// ---------------------------------------------------------------------------
// Local windowed attention, fixed-max softmax (|s| <= 8 by construction:
// q,k l2-normalized and the xPos decay factor is <=1 for all unmasked (i,j)).
// Block = 128 q-rows, wave = 32 rows (2 m-tiles). K/V chunks of 128 in LDS.
// ---------------------------------------------------------------------------
__global__ __launch_bounds__(256) void attn_kernel(const bf16* __restrict__ q,
                                                   const bf16* __restrict__ k,
                                                   const bf16* __restrict__ v,
                                                   bf16* __restrict__ o) {
    __shared__ __align__(16) bf16 Ks[128 * 64];
    __shared__ __align__(16) bf16 Vt[64][136];
    __shared__ __align__(16) bf16 Ps[4][16][136];
    const int tid  = threadIdx.x;
    const int wid  = tid >> 6;
    const int lane = tid & 63;
    const int quad = lane >> 4;
    const int l16  = lane & 15;
    const int lid = (blockIdx.x & 7) * 128 + (blockIdx.x >> 3);
    const int bh  = lid >> 6;
    const int q0  = (lid & 63) * 128;
    const size_t base = (size_t)bh * 8192;

    bf16x8 aq[2][2];
#pragma unroll
    for (int mt = 0; mt < 2; ++mt) {
        int qrow = q0 + wid * 32 + mt * 16 + l16;
        const bf16* qp = q + (base + qrow) * 64 + quad * 8;
        aq[mt][0] = *(const bf16x8*)qp;
        aq[mt][1] = *(const bf16x8*)(qp + 32);
    }
    f32x4 z4 = {0.f, 0.f, 0.f, 0.f};
    f32x4 accO[2][4];
    float rs[2][4];
#pragma unroll
    for (int mt = 0; mt < 2; ++mt)
#pragma unroll
        for (int j = 0; j < 4; ++j) { accO[mt][j] = z4; rs[mt][j] = 0.f; }

    int klo = q0 - 512;
    if (klo < 0) klo = 0;
    for (int kc = klo; kc < q0 + 128; kc += 128) {
        __syncthreads();
#pragma unroll
        for (int p = 0; p < 4; ++p) {
            int c   = tid + (p << 8);
            int row = c >> 3;
            int g   = (c & 7) ^ (row & 7);
            gld16(k + (base + kc + row) * 64 + g * 8, Ks + c * 8);
        }
        {
            int kp = lane;
#pragma unroll
            for (int w2 = 0; w2 < 2; ++w2) {
                int dc = wid * 2 + w2;
                const bf16* vp = v + (base + kc + kp * 2) * 64 + dc * 8;
                union { uint4 u; bf16 h[8]; } va, vb2;
                va.u  = *(const uint4*)vp;
                vb2.u = *(const uint4*)(vp + 64);
#pragma unroll
                for (int j = 0; j < 8; ++j)
                    *(unsigned*)&Vt[dc * 8 + j][kp * 2] =
                        pack_bf16x2(va.h[j], vb2.h[j]);
            }
        }
        __syncthreads();
#pragma unroll
        for (int mt = 0; mt < 2; ++mt) {
            f32x4 s[8];
#pragma unroll
            for (int ns = 0; ns < 8; ++ns) {
                int row = ns * 16 + l16;
                bf16x8 b0 = *(const bf16x8*)(Ks + row * 64 + ((quad    ) ^ (row & 7)) * 8);
                bf16x8 b1 = *(const bf16x8*)(Ks + row * 64 + ((4 + quad) ^ (row & 7)) * 8);
                f32x4 t = z4;
                t = MFMA16(aq[mt][0], b0, t);
                t = MFMA16(aq[mt][1], b1, t);
                s[ns] = t;
            }
            int gi0 = q0 + wid * 32 + mt * 16 + quad * 4;
#pragma unroll
            for (int ns = 0; ns < 8; ++ns) {
                int gj = kc + ns * 16 + l16;
#pragma unroll
                for (int r = 0; r < 4; ++r) {
                    int e = gi0 + r - gj;  // valid iff 0 <= e <= 512
                    float p = __builtin_exp2f(
                        fmaf(s[ns][r], 11.541560327f, -11.541560327f));
                    p = ((unsigned)e <= 512u) ? p : 0.f;
                    rs[mt][r] += p;
                    Ps[wid][quad * 4 + r][ns * 16 + l16] = (bf16)p;
                }
            }
#pragma unroll
            for (int ks2 = 0; ks2 < 4; ++ks2) {
                bf16x8 ap = *(const bf16x8*)&Ps[wid][l16][ks2 * 32 + quad * 8];
#pragma unroll
                for (int ds = 0; ds < 4; ++ds) {
                    bf16x8 bv = *(const bf16x8*)&Vt[ds * 16 + l16][ks2 * 32 + quad * 8];
                    accO[mt][ds] = MFMA16(ap, bv, accO[mt][ds]);
                }
            }
        }
    }
#pragma unroll
    for (int mt = 0; mt < 2; ++mt)
#pragma unroll
        for (int r = 0; r < 4; ++r) {
            float t = rs[mt][r];
            t += __shfl_xor(t, 1, 64);
            t += __shfl_xor(t, 2, 64);
            t += __shfl_xor(t, 4, 64);
            t += __shfl_xor(t, 8, 64);
            rs[mt][r] = 1.0f / t;
        }
    int bb = bh >> 3, hh = bh & 7;
#pragma unroll
    for (int mt = 0; mt < 2; ++mt)
#pragma unroll
        for (int ds = 0; ds < 4; ++ds)
#pragma unroll
            for (int r = 0; r < 4; ++r) {
                int m = q0 + wid * 32 + mt * 16 + quad * 4 + r;
                o[((size_t)(bb * 8192 + m)) * 512 + hh * 64 + ds * 16 + l16] =
                    (bf16)(accO[mt][ds][r] * rs[mt][r]);
            }
}

// ---------------------------------------------------------------------------
// FF1: fused dual-half (a + gate) GEMM + exact GELU -> act [16384][1408] bf16
// ---------------------------------------------------------------------------
__global__ __launch_bounds__(256) void ff1_kernel(const bf16* __restrict__ A,
                                                  const bf16* __restrict__ W1T,
                                                  const float* __restrict__ b1,
                                                  bf16* __restrict__ act) {
    __shared__ __align__(16) bf16 As[128 * 64];
    __shared__ __align__(16) bf16 Bsa[64 * 64];
    __shared__ __align__(16) bf16 Bsg[64 * 64];
    const int tid  = threadIdx.x;
    const int wid  = tid >> 6;
    const int lane = tid & 63;
    const int quad = lane >> 4;
    const int l16  = lane & 15;
    const int wm   = wid >> 1;
    const int wn   = wid & 1;
    const int m0   = blockIdx.y * 128;
    const int n0   = blockIdx.x * 64;

    f32x4 z4 = {0.f, 0.f, 0.f, 0.f};
    f32x4 aa[4][2], ag[4][2];
#pragma unroll
    for (int i = 0; i < 4; ++i)
#pragma unroll
        for (int j = 0; j < 2; ++j) { aa[i][j] = z4; ag[i][j] = z4; }

    for (int kt = 0; kt < 512; kt += 64) {
        __syncthreads();
#pragma unroll
        for (int p = 0; p < 4; ++p) {
            int c   = tid + (p << 8);
            int row = c >> 3;
            int g   = (c & 7) ^ (row & 7);
            gld16(A + (size_t)(m0 + row) * 512 + kt + g * 8, As + c * 8);
        }
#pragma unroll
        for (int p = 0; p < 2; ++p) {
            int c   = tid + (p << 8);
            int row = c >> 3;
            int g   = (c & 7) ^ (row & 7);
            gld16(W1T + (size_t)(n0 + row) * 512 + kt + g * 8, Bsa + c * 8);
            gld16(W1T + (size_t)(1365 + n0 + row) * 512 + kt + g * 8, Bsg + c * 8);
        }
        __syncthreads();
#pragma unroll
        for (int ks = 0; ks < 2; ++ks) {
            bf16x8 af[4];
#pragma unroll
            for (int i = 0; i < 4; ++i) {
                int r = wm * 64 + i * 16 + l16;
                af[i] = *(const bf16x8*)(As + r * 64 + ((((ks << 2) + quad)) ^ (r & 7)) * 8);
            }
#pragma unroll
            for (int j = 0; j < 2; ++j) {
                int r = wn * 32 + j * 16 + l16;
                int sl = (((ks << 2) + quad)) ^ (r & 7);
                bf16x8 ba = *(const bf16x8*)(Bsa + r * 64 + sl * 8);
                bf16x8 bg = *(const bf16x8*)(Bsg + r * 64 + sl * 8);
#pragma unroll
                for (int i = 0; i < 4; ++i) {
                    aa[i][j] = MFMA16(af[i], ba, aa[i][j]);
                    ag[i][j] = MFMA16(af[i], bg, ag[i][j]);
                }
            }
        }
    }

#pragma unroll
    for (int i = 0; i < 4; ++i)
#pragma unroll
        for (int j = 0; j < 2; ++j)
#pragma unroll
            for (int r = 0; r < 4; ++r) {
                int m  = m0 + wm * 64 + i * 16 + quad * 4 + r;
                int n  = n0 + wn * 32 + j * 16 + l16;
                bf16 outv = (bf16)0.f;
                if (n < 1365) {
                    float av = aa[i][j][r] + b1[n];
                    float gv = ag[i][j][r] + b1[1365 + n];
                    float gel = 0.5f * gv * (1.0f + erff(gv * 0.70710678118f));
                    outv = (bf16)(av * gel);
                }
                act[(size_t)m * 1408 + n] = outv;
            }
}

// ---------------------------------------------------------------------------
// Launch
// ---------------------------------------------------------------------------
extern "C" void kernel_launch(void* const* d_in, const int* in_sizes, int n_in,
                              void* d_out, int out_size, void* d_ws, size_t ws_size,
                              hipStream_t stream) {
    const float* x      = (const float*)d_in[0];
    const float* ln1g   = (const float*)d_in[1];
    const float* ln1b   = (const float*)d_in[2];
    const float* Wqkv   = (const float*)d_in[3];
    const float* qscale = (const float*)d_in[4];
    const float* kscale = (const float*)d_in[5];
    const float* Wout   = (const float*)d_in[6];
    const float* ln2g   = (const float*)d_in[7];
    const float* ln2b   = (const float*)d_in[8];
    const float* W1     = (const float*)d_in[9];
    const float* b1     = (const float*)d_in[10];
    const float* W2     = (const float*)d_in[11];
    const float* b2     = (const float*)d_in[12];
    float* out = (float*)d_out;

    char* ws = (char*)d_ws;
    const size_t MB = 1024 * 1024;
    bf16* h   = (bf16*)(ws);             // 16 MB (reused: attn out o, then h2)
    bf16* qb  = (bf16*)(ws + 16 * MB);   // q/k/v contiguous 16..64 MB
    bf16* kb  = (bf16*)(ws + 32 * MB);
    bf16* vb  = (bf16*)(ws + 48 * MB);
    bf16* wts = (bf16*)(ws + 64 * MB);   // bf16 transposed weights, ~6.2 MB
    bf16* WqkvT = wts;                   // [1536][512]
    bf16* WoutT = WqkvT + 1536 * 512;    // [512][512]
    bf16* W1T   = WoutT + 512 * 512;     // [2816][512] (rows >=2730 zero)
    bf16* W2T   = W1T + 2816 * 512;      // [512][1408] (cols >=1365 zero)
    bf16* ob  = h;
    bf16* h2  = h;
    bf16* act = qb;                      // 46.2 MB over dead q/k/v
    float* x1 = out;                     // pre-FF residual lives in d_out

    // 0. weight prep (fp32 [K][N] -> bf16 [N][Kpad])
    tcvt_kernel<<<dim3(16, 48), dim3(32, 8), 0, stream>>>(Wqkv, WqkvT, 512, 1536, 512, 1536);
    tcvt_kernel<<<dim3(16, 16), dim3(32, 8), 0, stream>>>(Wout, WoutT, 512, 512, 512, 512);
    tcvt_kernel<<<dim3(16, 88), dim3(32, 8), 0, stream>>>(W1, W1T, 512, 2730, 512, 2816);
    tcvt_kernel<<<dim3(44, 16), dim3(32, 8), 0, stream>>>(W2, W2T, 1365, 512, 1408, 512);
    // 1. LN1
    ln_kernel<<<4096, 256, 0, stream>>>(x, ln1g, ln1b, h);
    // 2. QKV GEMM with fused l2norm+scale+rotary epilogue -> per-head q/k/v
    gemm_bt<0><<<dim3(12, 128), 256, 0, stream>>>(h, WqkvT, 512, qb, nullptr,
                                                  qscale, kscale);
    // 3. local attention (128-row q-tiles, XCD-swizzled flat grid)
    attn_kernel<<<1024, 256, 0, stream>>>(qb, kb, vb, ob);
    // 4. out-proj + residual -> x1 (d_out, fp32)
    gemm_bt<1><<<dim3(4, 128), 256, 0, stream>>>(ob, WoutT, 512, nullptr, x1, x, nullptr);
    // 5. LN2 (reads d_out)
    ln_kernel<<<4096, 256, 0, stream>>>(x1, ln2g, ln2b, h2);
    // 6. FF1 fused dual-half + exact gelu -> act
    ff1_kernel<<<dim3(22, 128), 256, 0, stream>>>(h2, W1T, b1, act);
    // 7. FF2 + b2 + residual (in-place on d_out)
    gemm_bt<2><<<dim3(4, 128), 256, 0, stream>>>(act, W2T, 1408, nullptr, out, x1, b2);
}